// Round 2
// baseline (287.172 us; speedup 1.0000x reference)
//
#include <hip/hip_runtime.h>

// LieRE: out[n,y,x,q,:] = in[n,y,x,q,:] @ expm(y_v*S0 + x_v*S1)
// N=32,H=32,W=32,h=16,d=64. Transpose symmetry: rot[31-y][31-x] = rot[y][x]^T.
//
// Round 5: TWO-DISPATCH SPLIT.
//  k1 liere_expm  (512 blocks, 256 thr, 55KB LDS): unchanged bf16x3-MFMA
//     scale-square expm; ends by writing the apply-ready A-matrix
//     (rot(pos)^T, bf16 row-major, 8KB) for both paired positions into
//     d_ws:  A[pos] at ws + pos*4096 ushorts,  pos = y*32+x (0..1023).
//  k2 liere_apply (2048 blocks, 256 thr, NO LDS, launch_bounds(256,5)):
//     pure streaming apply at ~20 waves/CU (fused version was stuck at
//     8 waves/CU by phase-1's LDS -> latency-bound, 1.25 TB/s effective).
//     bf16 pack via v_cvt_pk_bf16_f32 (32 instr/iter vs ~320 VALU ops).
// Fallback: if ws_size < 8MB, the round-4 fused kernel runs unchanged.
// NOTE: batch (n) stride is H*W*h*d = 1<<20 floats.

typedef float f4 __attribute__((ext_vector_type(4)));
typedef short s8v __attribute__((ext_vector_type(8)));
typedef float f32x4 __attribute__((ext_vector_type(4)));
typedef unsigned short ush;
typedef unsigned int u32;
typedef ush us4 __attribute__((ext_vector_type(4)));

constexpr int LST = 68;          // fp32 staging stride (floats)
constexpr int BST = 72;          // bf16 row stride (ushorts); 144B rows, 16B-aligned
constexpr int SLOT = 64 * BST;   // one 64x64 bf16 matrix (ushorts)

static __device__ __forceinline__ ush f2bf(float f) {
    u32 u = __float_as_uint(f);
    u += 0x7fffu + ((u >> 16) & 1u);
    return (ush)(u >> 16);
}
static __device__ __forceinline__ float bf2f(ush h) {
    return __uint_as_float(((u32)h) << 16);
}
static __device__ __forceinline__ s8v negbf(s8v v) {
    u32* p = (u32*)&v;
#pragma unroll
    for (int i = 0; i < 4; ++i) p[i] ^= 0x80008000u;
    return v;
}
// packed f32->bf16 (RNE), lo16 = bf16(a), hi16 = bf16(b)
static __device__ __forceinline__ u32 cvtpk(float a, float b) {
    u32 r;
    asm("v_cvt_pk_bf16_f32 %0, %1, %2" : "=v"(r) : "v"(a), "v"(b));
    return r;
}

// Load this wave's 2x2x2 [tile][kslice][hi/lo] A/B fragments from a
// row-major bf16 (hi,lo) matrix. Rows base+t*16+m, k = ks*32 + q4*8 .. +7.
static __device__ __forceinline__ void load_frag(
    s8v fr[2][2][2], const ush* __restrict__ ah, const ush* __restrict__ al,
    int m, int q4, int base, bool neg)
{
#pragma unroll
    for (int t = 0; t < 2; ++t)
#pragma unroll
        for (int ks = 0; ks < 2; ++ks) {
            const int off = (base + t * 16 + m) * BST + ks * 32 + q4 * 8;
            s8v h = *(const s8v*)&ah[off];
            s8v l = *(const s8v*)&al[off];
            if (neg) { h = negbf(h); l = negbf(l); }
            fr[t][ks][0] = h;
            fr[t][ks][1] = l;
        }
}

// dst = Q * P^T + cdiag*I   (all row-major, bf16 hi/lo split, fp32 acc).
static __device__ __forceinline__ void mm_pre(
    ush* __restrict__ dh, ush* __restrict__ dl,
    const s8v pa[2][2][2],
    const ush* __restrict__ qh, const ush* __restrict__ ql,
    float cdiag, int m, int q4, int DM, int DN)
{
    s8v qb[2][2][2];
    load_frag(qb, qh, ql, m, q4, DN, false);

    f32x4 acc[2][2];
#pragma unroll
    for (int mt = 0; mt < 2; ++mt)
#pragma unroll
        for (int nt = 0; nt < 2; ++nt) acc[mt][nt] = (f32x4){0.f, 0.f, 0.f, 0.f};

#pragma unroll
    for (int ks = 0; ks < 2; ++ks)
#pragma unroll
        for (int mt = 0; mt < 2; ++mt)
#pragma unroll
            for (int nt = 0; nt < 2; ++nt) {
                acc[mt][nt] = __builtin_amdgcn_mfma_f32_16x16x32_bf16(
                    pa[mt][ks][0], qb[nt][ks][0], acc[mt][nt], 0, 0, 0);
                acc[mt][nt] = __builtin_amdgcn_mfma_f32_16x16x32_bf16(
                    pa[mt][ks][0], qb[nt][ks][1], acc[mt][nt], 0, 0, 0);
                acc[mt][nt] = __builtin_amdgcn_mfma_f32_16x16x32_bf16(
                    pa[mt][ks][1], qb[nt][ks][0], acc[mt][nt], 0, 0, 0);
            }

#pragma unroll
    for (int mt = 0; mt < 2; ++mt)
#pragma unroll
        for (int nt = 0; nt < 2; ++nt) {
            const int gm = DM + mt * 16 + q4 * 4;   // dst col base (4 regs)
            const int gn = DN + nt * 16 + m;        // dst row
            us4 h4, l4;
#pragma unroll
            for (int r = 0; r < 4; ++r) {
                float v = acc[mt][nt][r];
                if (gn == gm + r) v += cdiag;
                const ush h = f2bf(v);
                h4[r] = h;
                l4[r] = f2bf(v - bf2f(h));
            }
            *(us4*)&dh[gn * BST + gm] = h4;
            *(us4*)&dl[gn * BST + gm] = l4;
        }
}

// dst = src^T (both row-major bf16 hi/lo).
static __device__ __forceinline__ void transp(
    ush* __restrict__ dh, ush* __restrict__ dl,
    const ush* __restrict__ sh, const ush* __restrict__ sl, int tid)
{
    const int r = tid & 63;
    const int k0 = (tid >> 6) << 4;
    s8v a0 = *(const s8v*)&sh[r * BST + k0];
    s8v a1 = *(const s8v*)&sh[r * BST + k0 + 8];
    s8v b0 = *(const s8v*)&sl[r * BST + k0];
    s8v b1 = *(const s8v*)&sl[r * BST + k0 + 8];
#pragma unroll
    for (int j = 0; j < 8; ++j) {
        dh[(k0 + j) * BST + r]     = ((const ush*)&a0)[j];
        dh[(k0 + j + 8) * BST + r] = ((const ush*)&a1)[j];
        dl[(k0 + j) * BST + r]     = ((const ush*)&b0)[j];
        dl[(k0 + j + 8) * BST + r] = ((const ush*)&b1)[j];
    }
}

// ==================== kernel 1: expm -> workspace ====================
__global__ __launch_bounds__(256, 2)
void liere_expm(const float* __restrict__ emb, ush* __restrict__ ws) {
    __shared__ __align__(16) ush buf[6 * SLOT];
    __shared__ float snorm;

    const int tid = threadIdx.x;
    const int p = blockIdx.x;          // 0..511
    const int y = p >> 5;              // 0..15
    const int x = p & 31;              // 0..31

    float* sG = (float*)(buf);              // gen scratch      (P0)
    float* sU = (float*)(buf + 2 * SLOT);   // emb[0] staging   (P1)
    float* sV = (float*)(buf + 4 * SLOT);   // emb[1] staging   (P2)

#pragma unroll
    for (int i = 0; i < 4; ++i) {
        int lin = i * 1024 + tid * 4;
        int r = lin >> 6, c = lin & 63;
        *(f4*)&sU[r * LST + c] = *(const f4*)&emb[lin];
        *(f4*)&sV[r * LST + c] = *(const f4*)&emb[4096 + lin];
    }
    __syncthreads();

    const float yv = (2.0f * (float)y - 31.0f) / 31.0f;
    const float xv = (2.0f * (float)x - 31.0f) / 31.0f;
    {
        const int r0 = (tid >> 4) << 2, c0 = (tid & 15) << 2;
#pragma unroll
        for (int i = 0; i < 4; ++i)
#pragma unroll
            for (int j = 0; j < 4; ++j) {
                int r = r0 + i, c = c0 + j;
                float s0, s1;
                if (r < c)      { s0 = sU[r * LST + c];  s1 = sV[r * LST + c]; }
                else if (r > c) { s0 = -sU[c * LST + r]; s1 = -sV[c * LST + r]; }
                else            { s0 = 0.f; s1 = 0.f; }
                sG[r * LST + c] = yv * s0 + xv * s1;
            }
    }
    __syncthreads();

    if (tid < 64) {
        float s = 0.f;
        for (int c = 0; c < 64; ++c) s += fabsf(sG[tid * LST + c]);
#pragma unroll
        for (int off = 32; off > 0; off >>= 1) s = fmaxf(s, __shfl_down(s, off, 64));
        if (tid == 0) snorm = s;
    }
    __syncthreads();
    int sq = 0;
    {
        float nm = snorm;
        if (nm > 1.0f) sq = (int)ceilf(log2f(nm));
        if (sq < 0) sq = 0;
        if (sq > 14) sq = 14;
    }
    const float scale = exp2f((float)(-sq));

    const float C9 = 2.75573192e-6f, C8 = 2.48015876e-5f, C7 = 1.98412701e-4f,
                C6 = 1.38888893e-3f, C5 = 8.33333377e-3f, C4 = 4.16666679e-2f,
                C3 = 0.166666672f,   C2 = 0.5f,           C1 = 1.0f, C0 = 1.0f;

    ush* Xh = buf + 2 * SLOT;  ush* Xl = buf + 3 * SLOT;   // X      (P1)
    ush* t_h = buf + 4 * SLOT; ush* t_l = buf + 5 * SLOT;  // T ping (P2)
    ush* u_h = buf + 0 * SLOT; ush* u_l = buf + 1 * SLOT;  // T pong (P0)

    {
        const int r0 = (tid >> 4) << 2, c0 = (tid & 15) << 2;
#pragma unroll
        for (int i = 0; i < 4; ++i)
#pragma unroll
            for (int j = 0; j < 4; ++j) {
                int r = r0 + i, c = c0 + j;
                float a = sG[r * LST + c] * scale;
                ush xh = f2bf(a);
                Xh[r * BST + c] = xh;
                Xl[r * BST + c] = f2bf(a - bf2f(xh));
                float t0 = C9 * a + ((r == c) ? C8 : 0.f);
                ush th = f2bf(t0);
                t_h[r * BST + c] = th;
                t_l[r * BST + c] = f2bf(t0 - bf2f(th));
            }
    }
    __syncthreads();

    const int lane = tid & 63;
    const int w = tid >> 6;
    const int m = lane & 15;
    const int q4 = lane >> 4;
    const int DM = (w & 1) * 32;
    const int DN = (w >> 1) * 32;

    s8v xf[2][2][2];
    load_frag(xf, Xh, Xl, m, q4, DM, true);

    const float cs[8] = {C7, C6, C5, C4, C3, C2, C1, C0};
#pragma unroll
    for (int s = 0; s < 8; ++s) {
        mm_pre(u_h, u_l, xf, t_h, t_l, cs[s], m, q4, DM, DN);
        __syncthreads();
        ush* th2 = t_h; t_h = u_h; u_h = th2;
        ush* tl2 = t_l; t_l = u_l; u_l = tl2;
    }
    ush* tt_h = Xh; ush* tt_l = Xl;
    transp(tt_h, tt_l, t_h, t_l, tid);
    __syncthreads();

    for (int i = 0; i < sq; ++i) {
        s8v af[2][2][2];
        load_frag(af, tt_h, tt_l, m, q4, DM, false);
        mm_pre(u_h, u_l, af, t_h, t_l, 0.f, m, q4, DM, DN);
        __syncthreads();
        transp(tt_h, tt_l, u_h, u_l, tid);
        __syncthreads();
        ush* th2 = t_h; t_h = u_h; u_h = th2;
        ush* tl2 = t_l; t_l = u_l; u_l = tl2;
    }
    // t_h = R row-major (bf16 hi), tt_h = R^T row-major.
    // A[pos(y,x)]       = rot(y,x)^T       = R^T  (tt_h)
    // A[pos(31-y,31-x)] = rot(31-y,31-x)^T = R    (t_h)
    {
        const int pos0 = y * 32 + x;
        const int pos1 = (31 - y) * 32 + (31 - x);
        ush* A0 = ws + (size_t)pos0 * 4096;
        ush* A1 = ws + (size_t)pos1 * 4096;
        const int r = tid >> 2;          // 0..63
        const int c = (tid & 3) << 4;    // 0,16,32,48
        s8v v0 = *(const s8v*)&tt_h[r * BST + c];
        s8v v1 = *(const s8v*)&tt_h[r * BST + c + 8];
        s8v w0 = *(const s8v*)&t_h[r * BST + c];
        s8v w1 = *(const s8v*)&t_h[r * BST + c + 8];
        *(s8v*)&A0[r * 64 + c] = v0;
        *(s8v*)&A0[r * 64 + c + 8] = v1;
        *(s8v*)&A1[r * 64 + c] = w0;
        *(s8v*)&A1[r * 64 + c + 8] = w1;
    }
}

// ==================== kernel 2: streaming apply ====================
// out^T(pos) = A(pos) * B:  A[m][k] from ws (row-major), B[k][n] = in[h=n][k].
// block b: posid = b>>1, n-half = b&1; wave w handles n = half*16 + w*4 .. +3.
__global__ __launch_bounds__(256, 5)
void liere_apply(const float* __restrict__ in, const ush* __restrict__ ws,
                 float* __restrict__ out) {
    const int tid = threadIdx.x;
    const int b = blockIdx.x;            // 0..2047
    const int posid = b >> 1;            // 0..1023
    const int half = b & 1;
    const int w = tid >> 6;
    const int lane = tid & 63;
    const int m = lane & 15;
    const int q4 = lane >> 4;

    const ush* RF = ws + (size_t)posid * 4096;
    s8v rf[4][2];
#pragma unroll
    for (int t = 0; t < 4; ++t) {
        rf[t][0] = *(const s8v*)&RF[(t * 16 + m) * 64 + q4 * 8];
        rf[t][1] = *(const s8v*)&RF[(t * 16 + m) * 64 + 32 + q4 * 8];
    }

    const size_t pos = (size_t)posid * 1024;
    const int n0 = half * 16 + w * 4;

    for (int i = 0; i < 4; ++i) {
        const int n = n0 + i;
        const size_t nb = (size_t)n << 20;   // n stride = H*W*h*d = 1<<20 floats
        const float* src = in + nb + pos + m * 64 + q4 * 8;
        f4 u0 = *(const f4*)src;
        f4 u1 = *(const f4*)(src + 4);
        f4 u2 = *(const f4*)(src + 32);
        f4 u3 = *(const f4*)(src + 36);

        union { s8v v; u32 wv[4]; } B0, B1;
        B0.wv[0] = cvtpk(u0.x, u0.y); B0.wv[1] = cvtpk(u0.z, u0.w);
        B0.wv[2] = cvtpk(u1.x, u1.y); B0.wv[3] = cvtpk(u1.z, u1.w);
        B1.wv[0] = cvtpk(u2.x, u2.y); B1.wv[1] = cvtpk(u2.z, u2.w);
        B1.wv[2] = cvtpk(u3.x, u3.y); B1.wv[3] = cvtpk(u3.z, u3.w);

        f32x4 acc0 = {0.f,0.f,0.f,0.f}, acc1 = acc0, acc2 = acc0, acc3 = acc0;
        acc0 = __builtin_amdgcn_mfma_f32_16x16x32_bf16(rf[0][0], B0.v, acc0, 0, 0, 0);
        acc0 = __builtin_amdgcn_mfma_f32_16x16x32_bf16(rf[0][1], B1.v, acc0, 0, 0, 0);
        acc1 = __builtin_amdgcn_mfma_f32_16x16x32_bf16(rf[1][0], B0.v, acc1, 0, 0, 0);
        acc1 = __builtin_amdgcn_mfma_f32_16x16x32_bf16(rf[1][1], B1.v, acc1, 0, 0, 0);
        acc2 = __builtin_amdgcn_mfma_f32_16x16x32_bf16(rf[2][0], B0.v, acc2, 0, 0, 0);
        acc2 = __builtin_amdgcn_mfma_f32_16x16x32_bf16(rf[2][1], B1.v, acc2, 0, 0, 0);
        acc3 = __builtin_amdgcn_mfma_f32_16x16x32_bf16(rf[3][0], B0.v, acc3, 0, 0, 0);
        acc3 = __builtin_amdgcn_mfma_f32_16x16x32_bf16(rf[3][1], B1.v, acc3, 0, 0, 0);

        float* dst = out + nb + pos + m * 64 + q4 * 4;
        f4 o0 = {acc0[0], acc0[1], acc0[2], acc0[3]};
        f4 o1 = {acc1[0], acc1[1], acc1[2], acc1[3]};
        f4 o2 = {acc2[0], acc2[1], acc2[2], acc2[3]};
        f4 o3 = {acc3[0], acc3[1], acc3[2], acc3[3]};
        *(f4*)(dst +  0) = o0;
        *(f4*)(dst + 16) = o1;
        *(f4*)(dst + 32) = o2;
        *(f4*)(dst + 48) = o3;
    }
}

// ==================== fallback: round-4 fused kernel ====================
__global__ __launch_bounds__(256, 2)
void liere_fused(const float* __restrict__ in, const float* __restrict__ emb,
                 float* __restrict__ out) {
    __shared__ __align__(16) ush buf[6 * SLOT];
    __shared__ float snorm;

    const int tid = threadIdx.x;
    const int p = blockIdx.x;
    const int y = p >> 5;
    const int x = p & 31;

    float* sG = (float*)(buf);
    float* sU = (float*)(buf + 2 * SLOT);
    float* sV = (float*)(buf + 4 * SLOT);

#pragma unroll
    for (int i = 0; i < 4; ++i) {
        int lin = i * 1024 + tid * 4;
        int r = lin >> 6, c = lin & 63;
        *(f4*)&sU[r * LST + c] = *(const f4*)&emb[lin];
        *(f4*)&sV[r * LST + c] = *(const f4*)&emb[4096 + lin];
    }
    __syncthreads();

    const float yv = (2.0f * (float)y - 31.0f) / 31.0f;
    const float xv = (2.0f * (float)x - 31.0f) / 31.0f;
    {
        const int r0 = (tid >> 4) << 2, c0 = (tid & 15) << 2;
#pragma unroll
        for (int i = 0; i < 4; ++i)
#pragma unroll
            for (int j = 0; j < 4; ++j) {
                int r = r0 + i, c = c0 + j;
                float s0, s1;
                if (r < c)      { s0 = sU[r * LST + c];  s1 = sV[r * LST + c]; }
                else if (r > c) { s0 = -sU[c * LST + r]; s1 = -sV[c * LST + r]; }
                else            { s0 = 0.f; s1 = 0.f; }
                sG[r * LST + c] = yv * s0 + xv * s1;
            }
    }
    __syncthreads();

    if (tid < 64) {
        float s = 0.f;
        for (int c = 0; c < 64; ++c) s += fabsf(sG[tid * LST + c]);
#pragma unroll
        for (int off = 32; off > 0; off >>= 1) s = fmaxf(s, __shfl_down(s, off, 64));
        if (tid == 0) snorm = s;
    }
    __syncthreads();
    int sq = 0;
    {
        float nm = snorm;
        if (nm > 1.0f) sq = (int)ceilf(log2f(nm));
        if (sq < 0) sq = 0;
        if (sq > 14) sq = 14;
    }
    const float scale = exp2f((float)(-sq));

    const float C9 = 2.75573192e-6f, C8 = 2.48015876e-5f, C7 = 1.98412701e-4f,
                C6 = 1.38888893e-3f, C5 = 8.33333377e-3f, C4 = 4.16666679e-2f,
                C3 = 0.166666672f,   C2 = 0.5f,           C1 = 1.0f, C0 = 1.0f;

    ush* Xh = buf + 2 * SLOT;  ush* Xl = buf + 3 * SLOT;
    ush* t_h = buf + 4 * SLOT; ush* t_l = buf + 5 * SLOT;
    ush* u_h = buf + 0 * SLOT; ush* u_l = buf + 1 * SLOT;

    {
        const int r0 = (tid >> 4) << 2, c0 = (tid & 15) << 2;
#pragma unroll
        for (int i = 0; i < 4; ++i)
#pragma unroll
            for (int j = 0; j < 4; ++j) {
                int r = r0 + i, c = c0 + j;
                float a = sG[r * LST + c] * scale;
                ush xh = f2bf(a);
                Xh[r * BST + c] = xh;
                Xl[r * BST + c] = f2bf(a - bf2f(xh));
                float t0 = C9 * a + ((r == c) ? C8 : 0.f);
                ush th = f2bf(t0);
                t_h[r * BST + c] = th;
                t_l[r * BST + c] = f2bf(t0 - bf2f(th));
            }
    }
    __syncthreads();

    const int lane = tid & 63;
    const int w = tid >> 6;
    const int m = lane & 15;
    const int q4 = lane >> 4;
    const int DM = (w & 1) * 32;
    const int DN = (w >> 1) * 32;

    s8v xf[2][2][2];
    load_frag(xf, Xh, Xl, m, q4, DM, true);

    const float cs[8] = {C7, C6, C5, C4, C3, C2, C1, C0};
#pragma unroll
    for (int s = 0; s < 8; ++s) {
        mm_pre(u_h, u_l, xf, t_h, t_l, cs[s], m, q4, DM, DN);
        __syncthreads();
        ush* th2 = t_h; t_h = u_h; u_h = th2;
        ush* tl2 = t_l; t_l = u_l; u_l = tl2;
    }
    ush* tt_h = Xh; ush* tt_l = Xl;
    transp(tt_h, tt_l, t_h, t_l, tid);
    __syncthreads();

    for (int i = 0; i < sq; ++i) {
        s8v af[2][2][2];
        load_frag(af, tt_h, tt_l, m, q4, DM, false);
        mm_pre(u_h, u_l, af, t_h, t_l, 0.f, m, q4, DM, DN);
        __syncthreads();
        transp(tt_h, tt_l, u_h, u_l, tid);
        __syncthreads();
        ush* th2 = t_h; t_h = u_h; u_h = th2;
        ush* tl2 = t_l; t_l = u_l; u_l = tl2;
    }

    const int pass = w >> 1;
    const int nbase = (w & 1) << 4;

    const ush* RF = pass ? t_h : tt_h;
    s8v rf[4][2];
#pragma unroll
    for (int t = 0; t < 4; ++t) {
        rf[t][0] = *(const s8v*)&RF[(t * 16 + m) * BST + q4 * 8];
        rf[t][1] = *(const s8v*)&RF[(t * 16 + m) * BST + 32 + q4 * 8];
    }

    const int yy = pass ? (31 - y) : y;
    const int xx = pass ? (31 - x) : x;
    const size_t pos = (size_t)(yy * 32 + xx) * 1024;

    for (int i = 0; i < 16; ++i) {
        const int n = nbase + i;
        const size_t nb = (size_t)n << 20;
        const float* src = in + nb + pos + m * 64 + q4 * 8;
        f4 u0 = *(const f4*)src;
        f4 u1 = *(const f4*)(src + 4);
        f4 u2 = *(const f4*)(src + 32);
        f4 u3 = *(const f4*)(src + 36);
        union { s8v v; u32 wv[4]; } B0, B1;
        B0.wv[0] = cvtpk(u0.x, u0.y); B0.wv[1] = cvtpk(u0.z, u0.w);
        B0.wv[2] = cvtpk(u1.x, u1.y); B0.wv[3] = cvtpk(u1.z, u1.w);
        B1.wv[0] = cvtpk(u2.x, u2.y); B1.wv[1] = cvtpk(u2.z, u2.w);
        B1.wv[2] = cvtpk(u3.x, u3.y); B1.wv[3] = cvtpk(u3.z, u3.w);

        f32x4 acc0 = {0.f,0.f,0.f,0.f}, acc1 = acc0, acc2 = acc0, acc3 = acc0;
        acc0 = __builtin_amdgcn_mfma_f32_16x16x32_bf16(rf[0][0], B0.v, acc0, 0, 0, 0);
        acc0 = __builtin_amdgcn_mfma_f32_16x16x32_bf16(rf[0][1], B1.v, acc0, 0, 0, 0);
        acc1 = __builtin_amdgcn_mfma_f32_16x16x32_bf16(rf[1][0], B0.v, acc1, 0, 0, 0);
        acc1 = __builtin_amdgcn_mfma_f32_16x16x32_bf16(rf[1][1], B1.v, acc1, 0, 0, 0);
        acc2 = __builtin_amdgcn_mfma_f32_16x16x32_bf16(rf[2][0], B0.v, acc2, 0, 0, 0);
        acc2 = __builtin_amdgcn_mfma_f32_16x16x32_bf16(rf[2][1], B1.v, acc2, 0, 0, 0);
        acc3 = __builtin_amdgcn_mfma_f32_16x16x32_bf16(rf[3][0], B0.v, acc3, 0, 0, 0);
        acc3 = __builtin_amdgcn_mfma_f32_16x16x32_bf16(rf[3][1], B1.v, acc3, 0, 0, 0);

        float* dst = out + nb + pos + m * 64 + q4 * 4;
        f4 o0 = {acc0[0], acc0[1], acc0[2], acc0[3]};
        f4 o1 = {acc1[0], acc1[1], acc1[2], acc1[3]};
        f4 o2 = {acc2[0], acc2[1], acc2[2], acc2[3]};
        f4 o3 = {acc3[0], acc3[1], acc3[2], acc3[3]};
        *(f4*)(dst +  0) = o0;
        *(f4*)(dst + 16) = o1;
        *(f4*)(dst + 32) = o2;
        *(f4*)(dst + 48) = o3;
    }
}

extern "C" void kernel_launch(void* const* d_in, const int* in_sizes, int n_in,
                              void* d_out, int out_size, void* d_ws, size_t ws_size,
                              hipStream_t stream) {
    (void)in_sizes; (void)n_in; (void)out_size;
    const float* in = (const float*)d_in[0];
    const float* emb = (const float*)d_in[1];
    float* out = (float*)d_out;
    const size_t need = (size_t)1024 * 4096 * sizeof(ush);   // 8 MB
    if (d_ws != nullptr && ws_size >= need) {
        ush* ws = (ush*)d_ws;
        hipLaunchKernelGGL(liere_expm, dim3(512), dim3(256), 0, stream, emb, ws);
        hipLaunchKernelGGL(liere_apply, dim3(2048), dim3(256), 0, stream, in, ws, out);
    } else {
        hipLaunchKernelGGL(liere_fused, dim3(512), dim3(256), 0, stream, in, emb, out);
    }
}

// Round 4
// 286.352 us; speedup vs baseline: 1.0029x; 1.0029x over previous
//
#include <hip/hip_runtime.h>

// LieRE: out[n,y,x,q,:] = in[n,y,x,q,:] @ expm(y_v*S0 + x_v*S1)
// N=32,H=32,W=32,h=16,d=64. Transpose symmetry: rot[31-y][31-x] = rot[y][x]^T.
//
// Round 7: resubmit of round 6 (bench infra failed twice; no counters).
// Round 6: apply rewritten for latency hiding. Round-5's apply (2048 blocks,
// 4 iters/wave, VGPR=32) was convoy-bound at 2.2 TB/s: all blocks resident,
// register-starved waves fully serialized load->drain->compute->store.
//  k2 liere_apply: 1024 blocks (block = posid, 4 blocks/CU, 16 waves/CU);
//     each wave owns 8 batch indices; fully-unrolled 3-slot register ring
//     issues loads for iter i+2 before computing iter i (8KB in flight/wave).
//     launch_bounds(256,4) -> ~128 VGPR budget. Nontemporal stores keep the
//     input L3-resident (FETCH was 77MB < 128MB input: L3 already helping).
//  k1 liere_expm unchanged (bf16x3 MFMA scale-and-square, writes rot^T
//     per position to ws: A[pos] at ws + pos*4096 ushorts).
// Fallback: if ws_size < 8MB, the round-4 fused kernel runs unchanged.
// NOTE: batch (n) stride is H*W*h*d = 1<<20 floats.

typedef float f4 __attribute__((ext_vector_type(4)));
typedef short s8v __attribute__((ext_vector_type(8)));
typedef float f32x4 __attribute__((ext_vector_type(4)));
typedef unsigned short ush;
typedef unsigned int u32;
typedef ush us4 __attribute__((ext_vector_type(4)));

constexpr int LST = 68;          // fp32 staging stride (floats)
constexpr int BST = 72;          // bf16 row stride (ushorts); 144B rows, 16B-aligned
constexpr int SLOT = 64 * BST;   // one 64x64 bf16 matrix (ushorts)

static __device__ __forceinline__ ush f2bf(float f) {
    u32 u = __float_as_uint(f);
    u += 0x7fffu + ((u >> 16) & 1u);
    return (ush)(u >> 16);
}
static __device__ __forceinline__ float bf2f(ush h) {
    return __uint_as_float(((u32)h) << 16);
}
static __device__ __forceinline__ s8v negbf(s8v v) {
    u32* p = (u32*)&v;
#pragma unroll
    for (int i = 0; i < 4; ++i) p[i] ^= 0x80008000u;
    return v;
}
// packed f32->bf16 (RNE), lo16 = bf16(a), hi16 = bf16(b)
static __device__ __forceinline__ u32 cvtpk(float a, float b) {
    u32 r;
    asm("v_cvt_pk_bf16_f32 %0, %1, %2" : "=v"(r) : "v"(a), "v"(b));
    return r;
}

// Load this wave's 2x2x2 [tile][kslice][hi/lo] A/B fragments from a
// row-major bf16 (hi,lo) matrix. Rows base+t*16+m, k = ks*32 + q4*8 .. +7.
static __device__ __forceinline__ void load_frag(
    s8v fr[2][2][2], const ush* __restrict__ ah, const ush* __restrict__ al,
    int m, int q4, int base, bool neg)
{
#pragma unroll
    for (int t = 0; t < 2; ++t)
#pragma unroll
        for (int ks = 0; ks < 2; ++ks) {
            const int off = (base + t * 16 + m) * BST + ks * 32 + q4 * 8;
            s8v h = *(const s8v*)&ah[off];
            s8v l = *(const s8v*)&al[off];
            if (neg) { h = negbf(h); l = negbf(l); }
            fr[t][ks][0] = h;
            fr[t][ks][1] = l;
        }
}

// dst = Q * P^T + cdiag*I   (all row-major, bf16 hi/lo split, fp32 acc).
static __device__ __forceinline__ void mm_pre(
    ush* __restrict__ dh, ush* __restrict__ dl,
    const s8v pa[2][2][2],
    const ush* __restrict__ qh, const ush* __restrict__ ql,
    float cdiag, int m, int q4, int DM, int DN)
{
    s8v qb[2][2][2];
    load_frag(qb, qh, ql, m, q4, DN, false);

    f32x4 acc[2][2];
#pragma unroll
    for (int mt = 0; mt < 2; ++mt)
#pragma unroll
        for (int nt = 0; nt < 2; ++nt) acc[mt][nt] = (f32x4){0.f, 0.f, 0.f, 0.f};

#pragma unroll
    for (int ks = 0; ks < 2; ++ks)
#pragma unroll
        for (int mt = 0; mt < 2; ++mt)
#pragma unroll
            for (int nt = 0; nt < 2; ++nt) {
                acc[mt][nt] = __builtin_amdgcn_mfma_f32_16x16x32_bf16(
                    pa[mt][ks][0], qb[nt][ks][0], acc[mt][nt], 0, 0, 0);
                acc[mt][nt] = __builtin_amdgcn_mfma_f32_16x16x32_bf16(
                    pa[mt][ks][0], qb[nt][ks][1], acc[mt][nt], 0, 0, 0);
                acc[mt][nt] = __builtin_amdgcn_mfma_f32_16x16x32_bf16(
                    pa[mt][ks][1], qb[nt][ks][0], acc[mt][nt], 0, 0, 0);
            }

#pragma unroll
    for (int mt = 0; mt < 2; ++mt)
#pragma unroll
        for (int nt = 0; nt < 2; ++nt) {
            const int gm = DM + mt * 16 + q4 * 4;   // dst col base (4 regs)
            const int gn = DN + nt * 16 + m;        // dst row
            us4 h4, l4;
#pragma unroll
            for (int r = 0; r < 4; ++r) {
                float v = acc[mt][nt][r];
                if (gn == gm + r) v += cdiag;
                const ush h = f2bf(v);
                h4[r] = h;
                l4[r] = f2bf(v - bf2f(h));
            }
            *(us4*)&dh[gn * BST + gm] = h4;
            *(us4*)&dl[gn * BST + gm] = l4;
        }
}

// dst = src^T (both row-major bf16 hi/lo).
static __device__ __forceinline__ void transp(
    ush* __restrict__ dh, ush* __restrict__ dl,
    const ush* __restrict__ sh, const ush* __restrict__ sl, int tid)
{
    const int r = tid & 63;
    const int k0 = (tid >> 6) << 4;
    s8v a0 = *(const s8v*)&sh[r * BST + k0];
    s8v a1 = *(const s8v*)&sh[r * BST + k0 + 8];
    s8v b0 = *(const s8v*)&sl[r * BST + k0];
    s8v b1 = *(const s8v*)&sl[r * BST + k0 + 8];
#pragma unroll
    for (int j = 0; j < 8; ++j) {
        dh[(k0 + j) * BST + r]     = ((const ush*)&a0)[j];
        dh[(k0 + j + 8) * BST + r] = ((const ush*)&a1)[j];
        dl[(k0 + j) * BST + r]     = ((const ush*)&b0)[j];
        dl[(k0 + j + 8) * BST + r] = ((const ush*)&b1)[j];
    }
}

// ==================== kernel 1: expm -> workspace ====================
__global__ __launch_bounds__(256, 2)
void liere_expm(const float* __restrict__ emb, ush* __restrict__ ws) {
    __shared__ __align__(16) ush buf[6 * SLOT];
    __shared__ float snorm;

    const int tid = threadIdx.x;
    const int p = blockIdx.x;          // 0..511
    const int y = p >> 5;              // 0..15
    const int x = p & 31;              // 0..31

    float* sG = (float*)(buf);              // gen scratch      (P0)
    float* sU = (float*)(buf + 2 * SLOT);   // emb[0] staging   (P1)
    float* sV = (float*)(buf + 4 * SLOT);   // emb[1] staging   (P2)

#pragma unroll
    for (int i = 0; i < 4; ++i) {
        int lin = i * 1024 + tid * 4;
        int r = lin >> 6, c = lin & 63;
        *(f4*)&sU[r * LST + c] = *(const f4*)&emb[lin];
        *(f4*)&sV[r * LST + c] = *(const f4*)&emb[4096 + lin];
    }
    __syncthreads();

    const float yv = (2.0f * (float)y - 31.0f) / 31.0f;
    const float xv = (2.0f * (float)x - 31.0f) / 31.0f;
    {
        const int r0 = (tid >> 4) << 2, c0 = (tid & 15) << 2;
#pragma unroll
        for (int i = 0; i < 4; ++i)
#pragma unroll
            for (int j = 0; j < 4; ++j) {
                int r = r0 + i, c = c0 + j;
                float s0, s1;
                if (r < c)      { s0 = sU[r * LST + c];  s1 = sV[r * LST + c]; }
                else if (r > c) { s0 = -sU[c * LST + r]; s1 = -sV[c * LST + r]; }
                else            { s0 = 0.f; s1 = 0.f; }
                sG[r * LST + c] = yv * s0 + xv * s1;
            }
    }
    __syncthreads();

    if (tid < 64) {
        float s = 0.f;
        for (int c = 0; c < 64; ++c) s += fabsf(sG[tid * LST + c]);
#pragma unroll
        for (int off = 32; off > 0; off >>= 1) s = fmaxf(s, __shfl_down(s, off, 64));
        if (tid == 0) snorm = s;
    }
    __syncthreads();
    int sq = 0;
    {
        float nm = snorm;
        if (nm > 1.0f) sq = (int)ceilf(log2f(nm));
        if (sq < 0) sq = 0;
        if (sq > 14) sq = 14;
    }
    const float scale = exp2f((float)(-sq));

    const float C9 = 2.75573192e-6f, C8 = 2.48015876e-5f, C7 = 1.98412701e-4f,
                C6 = 1.38888893e-3f, C5 = 8.33333377e-3f, C4 = 4.16666679e-2f,
                C3 = 0.166666672f,   C2 = 0.5f,           C1 = 1.0f, C0 = 1.0f;

    ush* Xh = buf + 2 * SLOT;  ush* Xl = buf + 3 * SLOT;   // X      (P1)
    ush* t_h = buf + 4 * SLOT; ush* t_l = buf + 5 * SLOT;  // T ping (P2)
    ush* u_h = buf + 0 * SLOT; ush* u_l = buf + 1 * SLOT;  // T pong (P0)

    {
        const int r0 = (tid >> 4) << 2, c0 = (tid & 15) << 2;
#pragma unroll
        for (int i = 0; i < 4; ++i)
#pragma unroll
            for (int j = 0; j < 4; ++j) {
                int r = r0 + i, c = c0 + j;
                float a = sG[r * LST + c] * scale;
                ush xh = f2bf(a);
                Xh[r * BST + c] = xh;
                Xl[r * BST + c] = f2bf(a - bf2f(xh));
                float t0 = C9 * a + ((r == c) ? C8 : 0.f);
                ush th = f2bf(t0);
                t_h[r * BST + c] = th;
                t_l[r * BST + c] = f2bf(t0 - bf2f(th));
            }
    }
    __syncthreads();

    const int lane = tid & 63;
    const int w = tid >> 6;
    const int m = lane & 15;
    const int q4 = lane >> 4;
    const int DM = (w & 1) * 32;
    const int DN = (w >> 1) * 32;

    s8v xf[2][2][2];
    load_frag(xf, Xh, Xl, m, q4, DM, true);

    const float cs[8] = {C7, C6, C5, C4, C3, C2, C1, C0};
#pragma unroll
    for (int s = 0; s < 8; ++s) {
        mm_pre(u_h, u_l, xf, t_h, t_l, cs[s], m, q4, DM, DN);
        __syncthreads();
        ush* th2 = t_h; t_h = u_h; u_h = th2;
        ush* tl2 = t_l; t_l = u_l; u_l = tl2;
    }
    ush* tt_h = Xh; ush* tt_l = Xl;
    transp(tt_h, tt_l, t_h, t_l, tid);
    __syncthreads();

    for (int i = 0; i < sq; ++i) {
        s8v af[2][2][2];
        load_frag(af, tt_h, tt_l, m, q4, DM, false);
        mm_pre(u_h, u_l, af, t_h, t_l, 0.f, m, q4, DM, DN);
        __syncthreads();
        transp(tt_h, tt_l, u_h, u_l, tid);
        __syncthreads();
        ush* th2 = t_h; t_h = u_h; u_h = th2;
        ush* tl2 = t_l; t_l = u_l; u_l = tl2;
    }
    // t_h = R row-major (bf16 hi), tt_h = R^T row-major.
    // A[pos(y,x)]       = rot(y,x)^T       = R^T  (tt_h)
    // A[pos(31-y,31-x)] = rot(31-y,31-x)^T = R    (t_h)
    {
        const int pos0 = y * 32 + x;
        const int pos1 = (31 - y) * 32 + (31 - x);
        ush* A0 = ws + (size_t)pos0 * 4096;
        ush* A1 = ws + (size_t)pos1 * 4096;
        const int r = tid >> 2;          // 0..63
        const int c = (tid & 3) << 4;    // 0,16,32,48
        s8v v0 = *(const s8v*)&tt_h[r * BST + c];
        s8v v1 = *(const s8v*)&tt_h[r * BST + c + 8];
        s8v w0 = *(const s8v*)&t_h[r * BST + c];
        s8v w1 = *(const s8v*)&t_h[r * BST + c + 8];
        *(s8v*)&A0[r * 64 + c] = v0;
        *(s8v*)&A0[r * 64 + c + 8] = v1;
        *(s8v*)&A1[r * 64 + c] = w0;
        *(s8v*)&A1[r * 64 + c + 8] = w1;
    }
}

// ==================== kernel 2: streaming apply ====================
// out^T(pos) = A(pos) * B:  A[m][k] from ws (row-major), B[k][n] = in[h=n][k].
// block = posid; wave w owns n = w*8 .. w*8+7 (8 iterations).
// 3-slot register ring: loads for iter i+2 issued before computing iter i.
__global__ __launch_bounds__(256, 4)
void liere_apply(const float* __restrict__ in, const ush* __restrict__ ws,
                 float* __restrict__ out) {
    const int tid = threadIdx.x;
    const int posid = blockIdx.x;        // 0..1023
    const int w = tid >> 6;
    const int lane = tid & 63;
    const int m = lane & 15;
    const int q4 = lane >> 4;

    const ush* RF = ws + (size_t)posid * 4096;
    s8v rf[4][2];
#pragma unroll
    for (int t = 0; t < 4; ++t) {
        rf[t][0] = *(const s8v*)&RF[(t * 16 + m) * 64 + q4 * 8];
        rf[t][1] = *(const s8v*)&RF[(t * 16 + m) * 64 + 32 + q4 * 8];
    }

    const size_t pos = (size_t)posid * 1024;
    const int n0 = w * 8;
    const int moff = m * 64 + q4 * 8;

    f4 u[3][4];   // 3-deep ring; all indices compile-time after full unroll

#define LIERE_LD(slot, it) do { \
        const size_t nb_ = (size_t)(n0 + (it)) << 20; \
        const float* s_ = in + nb_ + pos + moff; \
        u[slot][0] = *(const f4*)s_; \
        u[slot][1] = *(const f4*)(s_ + 4); \
        u[slot][2] = *(const f4*)(s_ + 32); \
        u[slot][3] = *(const f4*)(s_ + 36); \
    } while (0)

    LIERE_LD(0, 0);
    LIERE_LD(1, 1);

#pragma unroll
    for (int i = 0; i < 8; ++i) {
        if (i + 2 < 8) {
            const int ps = (i + 2) % 3;
            LIERE_LD(ps, i + 2);
        }
        const int s = i % 3;

        union { s8v v; u32 wv[4]; } B0, B1;
        B0.wv[0] = cvtpk(u[s][0].x, u[s][0].y); B0.wv[1] = cvtpk(u[s][0].z, u[s][0].w);
        B0.wv[2] = cvtpk(u[s][1].x, u[s][1].y); B0.wv[3] = cvtpk(u[s][1].z, u[s][1].w);
        B1.wv[0] = cvtpk(u[s][2].x, u[s][2].y); B1.wv[1] = cvtpk(u[s][2].z, u[s][2].w);
        B1.wv[2] = cvtpk(u[s][3].x, u[s][3].y); B1.wv[3] = cvtpk(u[s][3].z, u[s][3].w);

        f32x4 acc0 = {0.f,0.f,0.f,0.f}, acc1 = acc0, acc2 = acc0, acc3 = acc0;
        acc0 = __builtin_amdgcn_mfma_f32_16x16x32_bf16(rf[0][0], B0.v, acc0, 0, 0, 0);
        acc0 = __builtin_amdgcn_mfma_f32_16x16x32_bf16(rf[0][1], B1.v, acc0, 0, 0, 0);
        acc1 = __builtin_amdgcn_mfma_f32_16x16x32_bf16(rf[1][0], B0.v, acc1, 0, 0, 0);
        acc1 = __builtin_amdgcn_mfma_f32_16x16x32_bf16(rf[1][1], B1.v, acc1, 0, 0, 0);
        acc2 = __builtin_amdgcn_mfma_f32_16x16x32_bf16(rf[2][0], B0.v, acc2, 0, 0, 0);
        acc2 = __builtin_amdgcn_mfma_f32_16x16x32_bf16(rf[2][1], B1.v, acc2, 0, 0, 0);
        acc3 = __builtin_amdgcn_mfma_f32_16x16x32_bf16(rf[3][0], B0.v, acc3, 0, 0, 0);
        acc3 = __builtin_amdgcn_mfma_f32_16x16x32_bf16(rf[3][1], B1.v, acc3, 0, 0, 0);

        const size_t nb = (size_t)(n0 + i) << 20;
        float* dst = out + nb + pos + m * 64 + q4 * 4;
        f4 o0 = {acc0[0], acc0[1], acc0[2], acc0[3]};
        f4 o1 = {acc1[0], acc1[1], acc1[2], acc1[3]};
        f4 o2 = {acc2[0], acc2[1], acc2[2], acc2[3]};
        f4 o3 = {acc3[0], acc3[1], acc3[2], acc3[3]};
        __builtin_nontemporal_store(o0, (f4*)(dst +  0));
        __builtin_nontemporal_store(o1, (f4*)(dst + 16));
        __builtin_nontemporal_store(o2, (f4*)(dst + 32));
        __builtin_nontemporal_store(o3, (f4*)(dst + 48));
    }
#undef LIERE_LD
}

// ==================== fallback: round-4 fused kernel ====================
__global__ __launch_bounds__(256, 2)
void liere_fused(const float* __restrict__ in, const float* __restrict__ emb,
                 float* __restrict__ out) {
    __shared__ __align__(16) ush buf[6 * SLOT];
    __shared__ float snorm;

    const int tid = threadIdx.x;
    const int p = blockIdx.x;
    const int y = p >> 5;
    const int x = p & 31;

    float* sG = (float*)(buf);
    float* sU = (float*)(buf + 2 * SLOT);
    float* sV = (float*)(buf + 4 * SLOT);

#pragma unroll
    for (int i = 0; i < 4; ++i) {
        int lin = i * 1024 + tid * 4;
        int r = lin >> 6, c = lin & 63;
        *(f4*)&sU[r * LST + c] = *(const f4*)&emb[lin];
        *(f4*)&sV[r * LST + c] = *(const f4*)&emb[4096 + lin];
    }
    __syncthreads();

    const float yv = (2.0f * (float)y - 31.0f) / 31.0f;
    const float xv = (2.0f * (float)x - 31.0f) / 31.0f;
    {
        const int r0 = (tid >> 4) << 2, c0 = (tid & 15) << 2;
#pragma unroll
        for (int i = 0; i < 4; ++i)
#pragma unroll
            for (int j = 0; j < 4; ++j) {
                int r = r0 + i, c = c0 + j;
                float s0, s1;
                if (r < c)      { s0 = sU[r * LST + c];  s1 = sV[r * LST + c]; }
                else if (r > c) { s0 = -sU[c * LST + r]; s1 = -sV[c * LST + r]; }
                else            { s0 = 0.f; s1 = 0.f; }
                sG[r * LST + c] = yv * s0 + xv * s1;
            }
    }
    __syncthreads();

    if (tid < 64) {
        float s = 0.f;
        for (int c = 0; c < 64; ++c) s += fabsf(sG[tid * LST + c]);
#pragma unroll
        for (int off = 32; off > 0; off >>= 1) s = fmaxf(s, __shfl_down(s, off, 64));
        if (tid == 0) snorm = s;
    }
    __syncthreads();
    int sq = 0;
    {
        float nm = snorm;
        if (nm > 1.0f) sq = (int)ceilf(log2f(nm));
        if (sq < 0) sq = 0;
        if (sq > 14) sq = 14;
    }
    const float scale = exp2f((float)(-sq));

    const float C9 = 2.75573192e-6f, C8 = 2.48015876e-5f, C7 = 1.98412701e-4f,
                C6 = 1.38888893e-3f, C5 = 8.33333377e-3f, C4 = 4.16666679e-2f,
                C3 = 0.166666672f,   C2 = 0.5f,           C1 = 1.0f, C0 = 1.0f;

    ush* Xh = buf + 2 * SLOT;  ush* Xl = buf + 3 * SLOT;
    ush* t_h = buf + 4 * SLOT; ush* t_l = buf + 5 * SLOT;
    ush* u_h = buf + 0 * SLOT; ush* u_l = buf + 1 * SLOT;

    {
        const int r0 = (tid >> 4) << 2, c0 = (tid & 15) << 2;
#pragma unroll
        for (int i = 0; i < 4; ++i)
#pragma unroll
            for (int j = 0; j < 4; ++j) {
                int r = r0 + i, c = c0 + j;
                float a = sG[r * LST + c] * scale;
                ush xh = f2bf(a);
                Xh[r * BST + c] = xh;
                Xl[r * BST + c] = f2bf(a - bf2f(xh));
                float t0 = C9 * a + ((r == c) ? C8 : 0.f);
                ush th = f2bf(t0);
                t_h[r * BST + c] = th;
                t_l[r * BST + c] = f2bf(t0 - bf2f(th));
            }
    }
    __syncthreads();

    const int lane = tid & 63;
    const int w = tid >> 6;
    const int m = lane & 15;
    const int q4 = lane >> 4;
    const int DM = (w & 1) * 32;
    const int DN = (w >> 1) * 32;

    s8v xf[2][2][2];
    load_frag(xf, Xh, Xl, m, q4, DM, true);

    const float cs[8] = {C7, C6, C5, C4, C3, C2, C1, C0};
#pragma unroll
    for (int s = 0; s < 8; ++s) {
        mm_pre(u_h, u_l, xf, t_h, t_l, cs[s], m, q4, DM, DN);
        __syncthreads();
        ush* th2 = t_h; t_h = u_h; u_h = th2;
        ush* tl2 = t_l; t_l = u_l; u_l = tl2;
    }
    ush* tt_h = Xh; ush* tt_l = Xl;
    transp(tt_h, tt_l, t_h, t_l, tid);
    __syncthreads();

    for (int i = 0; i < sq; ++i) {
        s8v af[2][2][2];
        load_frag(af, tt_h, tt_l, m, q4, DM, false);
        mm_pre(u_h, u_l, af, t_h, t_l, 0.f, m, q4, DM, DN);
        __syncthreads();
        transp(tt_h, tt_l, u_h, u_l, tid);
        __syncthreads();
        ush* th2 = t_h; t_h = u_h; u_h = th2;
        ush* tl2 = t_l; t_l = u_l; u_l = tl2;
    }

    const int pass = w >> 1;
    const int nbase = (w & 1) << 4;

    const ush* RF = pass ? t_h : tt_h;
    s8v rf[4][2];
#pragma unroll
    for (int t = 0; t < 4; ++t) {
        rf[t][0] = *(const s8v*)&RF[(t * 16 + m) * BST + q4 * 8];
        rf[t][1] = *(const s8v*)&RF[(t * 16 + m) * BST + 32 + q4 * 8];
    }

    const int yy = pass ? (31 - y) : y;
    const int xx = pass ? (31 - x) : x;
    const size_t pos = (size_t)(yy * 32 + xx) * 1024;

    for (int i = 0; i < 16; ++i) {
        const int n = nbase + i;
        const size_t nb = (size_t)n << 20;
        const float* src = in + nb + pos + m * 64 + q4 * 8;
        f4 u0 = *(const f4*)src;
        f4 u1 = *(const f4*)(src + 4);
        f4 u2 = *(const f4*)(src + 32);
        f4 u3 = *(const f4*)(src + 36);
        union { s8v v; u32 wv[4]; } B0, B1;
        B0.wv[0] = cvtpk(u0.x, u0.y); B0.wv[1] = cvtpk(u0.z, u0.w);
        B0.wv[2] = cvtpk(u1.x, u1.y); B0.wv[3] = cvtpk(u1.z, u1.w);
        B1.wv[0] = cvtpk(u2.x, u2.y); B1.wv[1] = cvtpk(u2.z, u2.w);
        B1.wv[2] = cvtpk(u3.x, u3.y); B1.wv[3] = cvtpk(u3.z, u3.w);

        f32x4 acc0 = {0.f,0.f,0.f,0.f}, acc1 = acc0, acc2 = acc0, acc3 = acc0;
        acc0 = __builtin_amdgcn_mfma_f32_16x16x32_bf16(rf[0][0], B0.v, acc0, 0, 0, 0);
        acc0 = __builtin_amdgcn_mfma_f32_16x16x32_bf16(rf[0][1], B1.v, acc0, 0, 0, 0);
        acc1 = __builtin_amdgcn_mfma_f32_16x16x32_bf16(rf[1][0], B0.v, acc1, 0, 0, 0);
        acc1 = __builtin_amdgcn_mfma_f32_16x16x32_bf16(rf[1][1], B1.v, acc1, 0, 0, 0);
        acc2 = __builtin_amdgcn_mfma_f32_16x16x32_bf16(rf[2][0], B0.v, acc2, 0, 0, 0);
        acc2 = __builtin_amdgcn_mfma_f32_16x16x32_bf16(rf[2][1], B1.v, acc2, 0, 0, 0);
        acc3 = __builtin_amdgcn_mfma_f32_16x16x32_bf16(rf[3][0], B0.v, acc3, 0, 0, 0);
        acc3 = __builtin_amdgcn_mfma_f32_16x16x32_bf16(rf[3][1], B1.v, acc3, 0, 0, 0);

        float* dst = out + nb + pos + m * 64 + q4 * 4;
        f4 o0 = {acc0[0], acc0[1], acc0[2], acc0[3]};
        f4 o1 = {acc1[0], acc1[1], acc1[2], acc1[3]};
        f4 o2 = {acc2[0], acc2[1], acc2[2], acc2[3]};
        f4 o3 = {acc3[0], acc3[1], acc3[2], acc3[3]};
        *(f4*)(dst +  0) = o0;
        *(f4*)(dst + 16) = o1;
        *(f4*)(dst + 32) = o2;
        *(f4*)(dst + 48) = o3;
    }
}

extern "C" void kernel_launch(void* const* d_in, const int* in_sizes, int n_in,
                              void* d_out, int out_size, void* d_ws, size_t ws_size,
                              hipStream_t stream) {
    (void)in_sizes; (void)n_in; (void)out_size;
    const float* in = (const float*)d_in[0];
    const float* emb = (const float*)d_in[1];
    float* out = (float*)d_out;
    const size_t need = (size_t)1024 * 4096 * sizeof(ush);   // 8 MB
    if (d_ws != nullptr && ws_size >= need) {
        ush* ws = (ush*)d_ws;
        hipLaunchKernelGGL(liere_expm, dim3(512), dim3(256), 0, stream, emb, ws);
        hipLaunchKernelGGL(liere_apply, dim3(1024), dim3(256), 0, stream, in, ws, out);
    } else {
        hipLaunchKernelGGL(liere_fused, dim3(512), dim3(256), 0, stream, in, emb, out);
    }
}

// Round 5
// 269.411 us; speedup vs baseline: 1.0659x; 1.0629x over previous
//
#include <hip/hip_runtime.h>

// LieRE: out[n,y,x,q,:] = in[n,y,x,q,:] @ expm(y_v*S0 + x_v*S1)
// N=32,H=32,W=32,h=16,d=64. Transpose symmetry: rot[31-y][31-x] = rot[y][x]^T.
//
// Round 8: back to ONE fused kernel (split kernels lost the expm/apply
// cross-block overlap that made round-1 the best per-byte performer), but
// with 2x the resident waves: 512 blocks x 512 threads (8 waves), LDS cut
// 55.3KB -> 36.9KB (4 slots) => 2 blocks/CU = 16 waves/CU (was 8).
// LDS diet:
//  - Horner/squaring matmuls are IN-PLACE: load fragments -> barrier ->
//    MFMA (regs) -> write same buffer -> barrier (same barrier count).
//  - R^T maintained by fusing a 32x ds_write_b16 scatter into the squaring
//    store phase (replaces the full transpose pass per squaring).
//  - gen built in REGISTERS from staged emb; inf-norm via shfl_xor tree +
//    16-slot LDS reduce (third fp32 staging buffer eliminated).
// expm tiling (8 waves): DM=(w&1)*32, DN=(w>>1)*16; per-wave acc 2x1 tiles.
// Apply: pair trick kept. Waves 0-3: pos(y,x) with R^T (pair B); waves 4-7:
// pos(31-y,31-x) with R (pair A). Each wave 8 n-chunks, plain loop, plain
// stores (NT stores measured +18MB write amplification, no gain).
// NOTE: batch (n) stride is H*W*h*d = 1<<20 floats.

typedef float f4 __attribute__((ext_vector_type(4)));
typedef short s8v __attribute__((ext_vector_type(8)));
typedef float f32x4 __attribute__((ext_vector_type(4)));
typedef unsigned short ush;
typedef unsigned int u32;
typedef ush us4 __attribute__((ext_vector_type(4)));

constexpr int LST = 68;          // fp32 staging stride (floats)
constexpr int BST = 72;          // bf16 row stride (ushorts)
constexpr int SLOT = 64 * BST;   // one 64x64 bf16 matrix (ushorts)

static __device__ __forceinline__ ush f2bf(float f) {
    u32 u = __float_as_uint(f);
    u += 0x7fffu + ((u >> 16) & 1u);
    return (ush)(u >> 16);
}
static __device__ __forceinline__ float bf2f(ush h) {
    return __uint_as_float(((u32)h) << 16);
}
static __device__ __forceinline__ s8v negbf(s8v v) {
    u32* p = (u32*)&v;
#pragma unroll
    for (int i = 0; i < 4; ++i) p[i] ^= 0x80008000u;
    return v;
}
static __device__ __forceinline__ u32 cvtpk(float a, float b) {
    u32 r;
    asm("v_cvt_pk_bf16_f32 %0, %1, %2" : "=v"(r) : "v"(a), "v"(b));
    return r;
}

// 2-tile fragment load (A-operand rows base..base+31), hi/lo, optional negate.
static __device__ __forceinline__ void load2(
    s8v fr[2][2][2], const ush* __restrict__ ah, const ush* __restrict__ al,
    int m, int q4, int base, bool neg)
{
#pragma unroll
    for (int t = 0; t < 2; ++t)
#pragma unroll
        for (int ks = 0; ks < 2; ++ks) {
            const int off = (base + t * 16 + m) * BST + ks * 32 + q4 * 8;
            s8v h = *(const s8v*)&ah[off];
            s8v l = *(const s8v*)&al[off];
            if (neg) { h = negbf(h); l = negbf(l); }
            fr[t][ks][0] = h;
            fr[t][ks][1] = l;
        }
}

// 1-tile fragment load (B-operand rows base..base+15), hi/lo.
static __device__ __forceinline__ void load1(
    s8v fr[2][2], const ush* __restrict__ ah, const ush* __restrict__ al,
    int m, int q4, int base)
{
#pragma unroll
    for (int ks = 0; ks < 2; ++ks) {
        const int off = (base + m) * BST + ks * 32 + q4 * 8;
        fr[ks][0] = *(const s8v*)&ah[off];
        fr[ks][1] = *(const s8v*)&al[off];
    }
}

// bf16x3 MFMA core: acc[mt] += pa[mt] * qb  (hh + hl + lh)
static __device__ __forceinline__ void mm_core(
    f32x4 acc[2], const s8v pa[2][2][2], const s8v qb[2][2])
{
#pragma unroll
    for (int ks = 0; ks < 2; ++ks)
#pragma unroll
        for (int mt = 0; mt < 2; ++mt) {
            acc[mt] = __builtin_amdgcn_mfma_f32_16x16x32_bf16(
                pa[mt][ks][0], qb[ks][0], acc[mt], 0, 0, 0);
            acc[mt] = __builtin_amdgcn_mfma_f32_16x16x32_bf16(
                pa[mt][ks][0], qb[ks][1], acc[mt], 0, 0, 0);
            acc[mt] = __builtin_amdgcn_mfma_f32_16x16x32_bf16(
                pa[mt][ks][1], qb[ks][0], acc[mt], 0, 0, 0);
        }
}

__global__ __launch_bounds__(512, 4)   // 4 waves/EU = 2 blocks/CU, VGPR<=128
void liere_fused2(const float* __restrict__ in, const float* __restrict__ emb,
                  float* __restrict__ out) {
    __shared__ __align__(16) ush buf[4 * SLOT];   // 36864 B
    __shared__ float sRed[16];

    const int tid = threadIdx.x;
    const int p = blockIdx.x;          // 0..511
    const int y = p >> 5;              // 0..15
    const int x = p & 31;              // 0..31

    ush* H_A = buf;              ush* L_A = buf + SLOT;       // pair A
    ush* H_B = buf + 2 * SLOT;   ush* L_B = buf + 3 * SLOT;   // pair B
    float* sE0 = (float*)buf;              // emb0 staging overlays pair A
    float* sE1 = (float*)(buf + 2 * SLOT); // emb1 staging overlays pair B

    // ---- stage emb0 -> sE0, emb1 -> sE1 (512 thr x 2 x f4) ----
#pragma unroll
    for (int i = 0; i < 2; ++i) {
        int lin = i * 2048 + tid * 4;
        int r = lin >> 6, c = lin & 63;
        *(f4*)&sE0[r * LST + c] = *(const f4*)&emb[lin];
        *(f4*)&sE1[r * LST + c] = *(const f4*)&emb[4096 + lin];
    }
    __syncthreads();

    // ---- gen in registers: thread owns 4 rows x 2 cols ----
    const float yv = (2.0f * (float)y - 31.0f) / 31.0f;
    const float xv = (2.0f * (float)x - 31.0f) / 31.0f;
    const int gr0 = (tid >> 5) << 2;    // 0..60
    const int gc0 = (tid & 31) << 1;    // 0..62
    float g[4][2];
    float rs[4];
#pragma unroll
    for (int i = 0; i < 4; ++i) {
        rs[i] = 0.f;
#pragma unroll
        for (int j = 0; j < 2; ++j) {
            int r = gr0 + i, c = gc0 + j;
            float s0, s1;
            if (r < c)      { s0 = sE0[r * LST + c];  s1 = sE1[r * LST + c]; }
            else if (r > c) { s0 = -sE0[c * LST + r]; s1 = -sE1[c * LST + r]; }
            else            { s0 = 0.f; s1 = 0.f; }
            float v = yv * s0 + xv * s1;
            g[i][j] = v;
            rs[i] += fabsf(v);
        }
    }
    // row sums across the 32-lane group sharing gr0 (same tid>>5)
#pragma unroll
    for (int off = 16; off > 0; off >>= 1) {
#pragma unroll
        for (int i = 0; i < 4; ++i) rs[i] += __shfl_xor(rs[i], off, 32);
    }
    {
        float mx = fmaxf(fmaxf(rs[0], rs[1]), fmaxf(rs[2], rs[3]));
        if ((tid & 31) == 0) sRed[tid >> 5] = mx;
    }
    __syncthreads();   // also guarantees all emb reads are done
    float nm = sRed[0];
#pragma unroll
    for (int k = 1; k < 16; ++k) nm = fmaxf(nm, sRed[k]);
    int sq = 0;
    if (nm > 1.0f) sq = (int)ceilf(log2f(nm));
    if (sq < 0) sq = 0;
    if (sq > 14) sq = 14;
    const float scale = exp2f((float)(-sq));

    const float C9 = 2.75573192e-6f, C8 = 2.48015876e-5f, C7 = 1.98412701e-4f,
                C6 = 1.38888893e-3f, C5 = 8.33333377e-3f, C4 = 4.16666679e-2f,
                C3 = 0.166666672f,   C2 = 0.5f,           C1 = 1.0f, C0 = 1.0f;

    // ---- write X (hi/lo) -> pair B, T0 = C9*X + C8*I -> pair A ----
#pragma unroll
    for (int i = 0; i < 4; ++i)
#pragma unroll
        for (int j = 0; j < 2; ++j) {
            int r = gr0 + i, c = gc0 + j;
            float a = g[i][j] * scale;
            ush xh = f2bf(a);
            H_B[r * BST + c] = xh;
            L_B[r * BST + c] = f2bf(a - bf2f(xh));
            float t0 = C9 * a + ((r == c) ? C8 : 0.f);
            ush th = f2bf(t0);
            H_A[r * BST + c] = th;
            L_A[r * BST + c] = f2bf(t0 - bf2f(th));
        }
    __syncthreads();

    const int lane = tid & 63;
    const int w = tid >> 6;            // 0..7
    const int m = lane & 15;
    const int q4 = lane >> 4;
    const int DM = (w & 1) * 32;       // A-op rows / dst cols
    const int DN = (w >> 1) * 16;      // B-op rows / dst rows (0,16,32,48)

    // hoist P = -X (= X^T) fragments for all Horner steps
    s8v xf[2][2][2];
    load2(xf, H_B, L_B, m, q4, DM, true);

    // ---- Horner: 8 in-place matmuls on pair A: newT = T*X + c*I ----
    const float cs[8] = {C7, C6, C5, C4, C3, C2, C1, C0};
    for (int s = 0; s < 8; ++s) {
        s8v qb[2][2];
        load1(qb, H_A, L_A, m, q4, DN);
        __syncthreads();                       // all reads of A done
        f32x4 acc[2];
        acc[0] = (f32x4){0.f, 0.f, 0.f, 0.f};
        acc[1] = acc[0];
        mm_core(acc, xf, qb);
#pragma unroll
        for (int mt = 0; mt < 2; ++mt) {
            const int gm = DM + mt * 16 + q4 * 4;
            const int gn = DN + m;
            us4 h4, l4;
#pragma unroll
            for (int r = 0; r < 4; ++r) {
                float v = acc[mt][r];
                if (gn == gm + r) v += cs[s];
                const ush h = f2bf(v);
                h4[r] = h;
                l4[r] = f2bf(v - bf2f(h));
            }
            *(us4*)&H_A[gn * BST + gm] = h4;
            *(us4*)&L_A[gn * BST + gm] = l4;
        }
        __syncthreads();
    }

    // ---- one-time transpose A -> B (T^T), 512 threads ----
    {
        const int r = tid & 63;
        const int k0 = (tid >> 6) << 3;        // 0..56
        s8v a0 = *(const s8v*)&H_A[r * BST + k0];
        s8v b0 = *(const s8v*)&L_A[r * BST + k0];
#pragma unroll
        for (int j = 0; j < 8; ++j) {
            H_B[(k0 + j) * BST + r] = ((const ush*)&a0)[j];
            L_B[(k0 + j) * BST + r] = ((const ush*)&b0)[j];
        }
    }
    __syncthreads();

    // ---- squarings: newS = S*S^T^T (Q=S from A, P=S^T from B), in place;
    //      S^T maintained by fused scatter into B ----
    for (int it = 0; it < sq; ++it) {
        s8v af[2][2][2];
        load2(af, H_B, L_B, m, q4, DM, false);
        s8v qb[2][2];
        load1(qb, H_A, L_A, m, q4, DN);
        __syncthreads();                       // all reads of A,B done
        f32x4 acc[2];
        acc[0] = (f32x4){0.f, 0.f, 0.f, 0.f};
        acc[1] = acc[0];
        mm_core(acc, af, qb);
#pragma unroll
        for (int mt = 0; mt < 2; ++mt) {
            const int gm = DM + mt * 16 + q4 * 4;
            const int gn = DN + m;
            us4 h4, l4;
#pragma unroll
            for (int r = 0; r < 4; ++r) {
                float v = acc[mt][r];
                const ush h = f2bf(v);
                h4[r] = h;
                l4[r] = f2bf(v - bf2f(h));
            }
            *(us4*)&H_A[gn * BST + gm] = h4;   // S
            *(us4*)&L_A[gn * BST + gm] = l4;
#pragma unroll
            for (int r = 0; r < 4; ++r) {      // S^T
                H_B[(gm + r) * BST + gn] = h4[r];
                L_B[(gm + r) * BST + gn] = l4[r];
            }
        }
        __syncthreads();
    }
    // pair A hi = R (row-major), pair B hi = R^T (row-major)

    // ---- apply: waves 0-3 -> pos(y,x) with R^T; waves 4-7 -> mirrored pos
    //      with R. Each wave: 8 n-chunks, plain streaming loop. ----
    const int pass = w >> 2;
    const int n0 = (w & 3) * 8;

    const ush* RF = pass ? H_A : H_B;
    s8v rf[4][2];
#pragma unroll
    for (int t = 0; t < 4; ++t) {
        rf[t][0] = *(const s8v*)&RF[(t * 16 + m) * BST + q4 * 8];
        rf[t][1] = *(const s8v*)&RF[(t * 16 + m) * BST + 32 + q4 * 8];
    }

    const int yy = pass ? (31 - y) : y;
    const int xx = pass ? (31 - x) : x;
    const size_t pos = (size_t)(yy * 32 + xx) * 1024;

    for (int i = 0; i < 8; ++i) {
        const int n = n0 + i;
        const size_t nb = (size_t)n << 20;   // n stride = 1<<20 floats
        const float* src = in + nb + pos + m * 64 + q4 * 8;
        f4 u0 = *(const f4*)src;
        f4 u1 = *(const f4*)(src + 4);
        f4 u2 = *(const f4*)(src + 32);
        f4 u3 = *(const f4*)(src + 36);

        union { s8v v; u32 wv[4]; } B0, B1;
        B0.wv[0] = cvtpk(u0.x, u0.y); B0.wv[1] = cvtpk(u0.z, u0.w);
        B0.wv[2] = cvtpk(u1.x, u1.y); B0.wv[3] = cvtpk(u1.z, u1.w);
        B1.wv[0] = cvtpk(u2.x, u2.y); B1.wv[1] = cvtpk(u2.z, u2.w);
        B1.wv[2] = cvtpk(u3.x, u3.y); B1.wv[3] = cvtpk(u3.z, u3.w);

        f32x4 acc0 = {0.f,0.f,0.f,0.f}, acc1 = acc0, acc2 = acc0, acc3 = acc0;
        acc0 = __builtin_amdgcn_mfma_f32_16x16x32_bf16(rf[0][0], B0.v, acc0, 0, 0, 0);
        acc0 = __builtin_amdgcn_mfma_f32_16x16x32_bf16(rf[0][1], B1.v, acc0, 0, 0, 0);
        acc1 = __builtin_amdgcn_mfma_f32_16x16x32_bf16(rf[1][0], B0.v, acc1, 0, 0, 0);
        acc1 = __builtin_amdgcn_mfma_f32_16x16x32_bf16(rf[1][1], B1.v, acc1, 0, 0, 0);
        acc2 = __builtin_amdgcn_mfma_f32_16x16x32_bf16(rf[2][0], B0.v, acc2, 0, 0, 0);
        acc2 = __builtin_amdgcn_mfma_f32_16x16x32_bf16(rf[2][1], B1.v, acc2, 0, 0, 0);
        acc3 = __builtin_amdgcn_mfma_f32_16x16x32_bf16(rf[3][0], B0.v, acc3, 0, 0, 0);
        acc3 = __builtin_amdgcn_mfma_f32_16x16x32_bf16(rf[3][1], B1.v, acc3, 0, 0, 0);

        float* dst = out + nb + pos + m * 64 + q4 * 4;
        f4 o0 = {acc0[0], acc0[1], acc0[2], acc0[3]};
        f4 o1 = {acc1[0], acc1[1], acc1[2], acc1[3]};
        f4 o2 = {acc2[0], acc2[1], acc2[2], acc2[3]};
        f4 o3 = {acc3[0], acc3[1], acc3[2], acc3[3]};
        *(f4*)(dst +  0) = o0;
        *(f4*)(dst + 16) = o1;
        *(f4*)(dst + 32) = o2;
        *(f4*)(dst + 48) = o3;
    }
}

extern "C" void kernel_launch(void* const* d_in, const int* in_sizes, int n_in,
                              void* d_out, int out_size, void* d_ws, size_t ws_size,
                              hipStream_t stream) {
    (void)in_sizes; (void)n_in; (void)out_size; (void)d_ws; (void)ws_size;
    const float* in = (const float*)d_in[0];
    const float* emb = (const float*)d_in[1];
    float* out = (float*)d_out;
    hipLaunchKernelGGL(liere_fused2, dim3(512), dim3(512), 0, stream, in, emb, out);
}